// Round 6
// baseline (77.994 us; speedup 1.0000x reference)
//
#include <hip/hip_runtime.h>

#define H 256
#define SEQ 2048
#define NBATCH 64
#define M_TOTAL (NBATCH * SEQ)   // 131072 rows
#define BM 32                    // rows per block (32KB LDS -> 5 blocks/CU)

using bf16x8 = __attribute__((ext_vector_type(8))) short;
using u16x4  = __attribute__((ext_vector_type(4))) unsigned short;
using f32x4  = __attribute__((ext_vector_type(4))) float;

__device__ __forceinline__ unsigned short f2bf(float x) {
    union { float f; unsigned u; } v; v.f = x;
    unsigned r = v.u + 0x7fffu + ((v.u >> 16) & 1u);   // RNE
    return (unsigned short)(r >> 16);
}
__device__ __forceinline__ float bf2f(unsigned short b) {
    union { unsigned u; float f; } v; v.u = ((unsigned)b) << 16;
    return v.f;
}
__device__ __forceinline__ float asf(unsigned u) { union { unsigned u; float f; } v; v.u = u; return v.f; }
__device__ __forceinline__ unsigned asu(float f) { union { float f; unsigned u; } v; v.f = f; return v.u; }

// Raw 16B global load pinned in registers: compiler cannot sink/collapse this.
__device__ __forceinline__ bf16x8 gload16(const void* p) {
    bf16x8 r;
    asm volatile("global_load_dwordx4 %0, %1, off" : "=v"(r) : "v"(p));
    return r;
}

// ---------------- prep 1: qpb[d] = sum_c q[c]*W2[c,d] + b1[d] + b2[d] ----------------
__global__ __launch_bounds__(256) void prep_qpb(const float* __restrict__ q,
                                                const float* __restrict__ W2,
                                                const float* __restrict__ b1,
                                                const float* __restrict__ b2,
                                                float* __restrict__ qpb) {
    int t = threadIdx.x;
    float s = 0.f;
#pragma unroll 8
    for (int c = 0; c < H; ++c) s = fmaf(q[c], W2[c * H + t], s);
    qpb[t] = s + b1[t] + b2[t];
}

// ---------------- prep 2: pack W1 into bf16 hi/lo MFMA fragment order --------------
// Layout (bf16x8-granules): frag(ct 0..15, ks 0..7, h 0..1)[lane 0..63]:
//   element j: W1split[h][k = ks*32 + (lane>>4)*8 + j][n = ct*16 + (lane&15)]
__global__ __launch_bounds__(256) void prep_bpack(const float* __restrict__ W1,
                                                  unsigned short* __restrict__ Bpack) {
    int tid = blockIdx.x * 256 + threadIdx.x;  // 0..8191 = (ct,ks,lane)
    int ct = tid >> 9;
    int ks = (tid >> 6) & 7;
    int l  = tid & 63;
    bf16x8 hi, lo;
#pragma unroll
    for (int j = 0; j < 8; ++j) {
        int kk = ks * 32 + ((l >> 4) & 3) * 8 + j;
        int nn = ct * 16 + (l & 15);
        float w = W1[kk * H + nn];
        unsigned short h = f2bf(w);
        float rem = w - bf2f(h);
        hi[j] = (short)h;
        lo[j] = (short)f2bf(rem);
    }
    bf16x8* out = (bf16x8*)Bpack;
    out[((ct * 8 + ks) * 2 + 0) * 64 + l] = hi;
    out[((ct * 8 + ks) * 2 + 1) * 64 + l] = lo;
}

// ---------------- main: scores[m] = sum_n tanh(k@W1 + qpb)[m,n] * V[n] ----------------
// Swapped GEMM C'[n,m], A = W1 frags (L2->reg, prefetch depth-1, counted vmcnt),
// B = k frags (LDS, 32 rows). 4 waves = 4 n-groups; wave owns 64 n x 32 m.
// Small barrier domain + 5 blocks/CU => independent-block overlap hides stalls.
__global__ __launch_bounds__(256, 5) void fused_main(const float* __restrict__ kin,
                                                     const unsigned short* __restrict__ Bpack,
                                                     const float* __restrict__ qpb,
                                                     const float* __restrict__ Vp,
                                                     float* __restrict__ out_scores) {
    // LDS: k_hi [32 m][256 k] bf16 (16 KB) + k_lo (16 KB), XOR-swizzled
    __shared__ __align__(16) unsigned char lds[32768];
    unsigned char* Khi = lds;
    unsigned char* Klo = lds + 16384;

    const int t  = threadIdx.x;          // 0..255
    const int m0 = blockIdx.x * BM;

    // ---- stage k tile: f32 -> bf16 hi/lo via truncation split ----
#pragma unroll
    for (int i = 0; i < 8; ++i) {
        int flat = i * 1024 + t * 4;      // covers [32][256] floats
        int r = flat >> 8;
        int c = flat & 255;
        const float4 v = *(const float4*)(kin + (m0 + r) * H + c);
        unsigned ux = asu(v.x), uy = asu(v.y), uz = asu(v.z), uw = asu(v.w);
        u16x4 hi = {(unsigned short)(ux >> 16), (unsigned short)(uy >> 16),
                    (unsigned short)(uz >> 16), (unsigned short)(uw >> 16)};
        u16x4 lo = {(unsigned short)(asu(v.x - asf(ux & 0xffff0000u)) >> 16),
                    (unsigned short)(asu(v.y - asf(uy & 0xffff0000u)) >> 16),
                    (unsigned short)(asu(v.z - asf(uz & 0xffff0000u)) >> 16),
                    (unsigned short)(asu(v.w - asf(uw & 0xffff0000u)) >> 16)};
        int addr = (r * 512 + c * 2) ^ ((r & 7) << 4);
        *(u16x4*)(Khi + addr) = hi;
        *(u16x4*)(Klo + addr) = lo;
    }
    __syncthreads();   // drains staging vmcnt -> manual counts below are exact

    const int wave = t >> 6;             // 0..3 = n-group (64 cols of W1)
    const int lane = t & 63;
    const int lhi  = lane >> 4;          // 0..3
    const int llo  = lane & 15;          // 0..15
    const int wn   = wave;

    f32x4 acc[4][2];   // [nt][mt]
#pragma unroll
    for (int a = 0; a < 4; ++a)
#pragma unroll
        for (int b = 0; b < 2; ++b) acc[a][b] = (f32x4){0.f, 0.f, 0.f, 0.f};

    // W1 frag byte offset for (nt, ks, h): (((wn*4+nt)*8+ks)*2+h)*1024 + lane*16
    const char* bbase = (const char*)Bpack + (size_t)lane * 16;

    bf16x8 w1[2][4];   // [slot][ntn*2 + h]; half Hh: ks=Hh>>1, nt=(Hh&1)*2+ntn
    bf16x8 kf[4];      // [mt*2 + h] for current ks

#define ISSUE_HALF(Hh, S)                                                          \
    do {                                                                           \
        const int ks_ = (Hh) >> 1, n0_ = ((Hh) & 1) * 2;                           \
        w1[S][0] = gload16(bbase + (((wn * 4 + n0_    ) * 8 + ks_) * 2 + 0) * 1024);\
        w1[S][1] = gload16(bbase + (((wn * 4 + n0_    ) * 8 + ks_) * 2 + 1) * 1024);\
        w1[S][2] = gload16(bbase + (((wn * 4 + n0_ + 1) * 8 + ks_) * 2 + 0) * 1024);\
        w1[S][3] = gload16(bbase + (((wn * 4 + n0_ + 1) * 8 + ks_) * 2 + 1) * 1024);\
    } while (0)

    // prologue: one half in flight
    ISSUE_HALF(0, 0);

#pragma unroll
    for (int Hh = 0; Hh < 16; ++Hh) {
        if ((Hh & 1) == 0) {
            // k-tile B-fragments for this ks (shared by both halves of ks)
            const int ks = Hh >> 1;
#pragma unroll
            for (int mt = 0; mt < 2; ++mt) {
                int ml = mt * 16 + llo;
                int byte = (ml * 512 + ks * 64 + lhi * 16) ^ ((ml & 7) << 4);
                kf[mt * 2 + 0] = *(const bf16x8*)(Khi + byte);
                kf[mt * 2 + 1] = *(const bf16x8*)(Klo + byte);
            }
        }
        if (Hh < 15) ISSUE_HALF(Hh + 1, (Hh + 1) & 1);
        // wait for current half's 4 loads; keep next half's 4 in flight
        if (Hh < 15) { asm volatile("s_waitcnt vmcnt(4)"); }
        else         { asm volatile("s_waitcnt vmcnt(0)"); }
        __builtin_amdgcn_sched_barrier(0);

        const int slot = Hh & 1;
        // 12 MFMAs, round-robin over the 4 independent acc chains
#pragma unroll
        for (int p = 0; p < 3; ++p) {
            const int ha = (p == 1) ? 1 : 0;   // w1 lo for p==1
            const int hb = (p == 2) ? 1 : 0;   // k  lo for p==2
#pragma unroll
            for (int ntn = 0; ntn < 2; ++ntn) {
                const int nt = (Hh & 1) * 2 + ntn;
#pragma unroll
                for (int mt = 0; mt < 2; ++mt)
                    acc[nt][mt] = __builtin_amdgcn_mfma_f32_16x16x32_bf16(
                        w1[slot][ntn * 2 + ha], kf[mt * 2 + hb], acc[nt][mt], 0, 0, 0);
            }
        }
    }
#undef ISSUE_HALF

    // ---- epilogue: tanh, *V, in-lane reduce over this wave's 64 n ----
    // C' layout: m = mt*16 + (lane&15), n = wn*64 + nt*16 + lhi*4 + i
    f32x4 qv[4], vv[4];
#pragma unroll
    for (int nt = 0; nt < 4; ++nt) {
        qv[nt] = *(const f32x4*)(qpb + wn * 64 + nt * 16 + lhi * 4);
        vv[nt] = *(const f32x4*)(Vp  + wn * 64 + nt * 16 + lhi * 4);
    }
    float sm[2] = {0.f, 0.f};
#pragma unroll
    for (int nt = 0; nt < 4; ++nt)
#pragma unroll
        for (int mt = 0; mt < 2; ++mt)
#pragma unroll
            for (int i = 0; i < 4; ++i) {
                float x = acc[nt][mt][i] + qv[nt][i];
                float e = __expf(2.f * x);
                float th = 1.f - 2.f * __builtin_amdgcn_rcpf(e + 1.f);
                sm[mt] += th * vv[nt][i];
            }
    // sum across the 4 lhi groups (lanes l, l^16, l^32, l^48)
#pragma unroll
    for (int mt = 0; mt < 2; ++mt) {
        sm[mt] += __shfl_xor(sm[mt], 16, 64);
        sm[mt] += __shfl_xor(sm[mt], 32, 64);
    }

    __syncthreads();                 // done with k region; reuse as partial buffer
    float* part = (float*)lds;       // [4 wn][32 m]
    if (lane < 16) {
        part[wn * 32 +  0 + lane] = sm[0];
        part[wn * 32 + 16 + lane] = sm[1];
    }
    __syncthreads();
    if (t < BM)
        out_scores[m0 + t] = part[t] + part[32 + t] + part[64 + t] + part[96 + t];
}

// ---------------- softmax over seq axis, in-place on d_out ----------------
__global__ __launch_bounds__(256) void softmax_kernel(float* __restrict__ out) {
    const int b = blockIdx.x;
    const int t = threadIdx.x;
    float* row = out + b * SEQ;
    float v[8];
#pragma unroll
    for (int j = 0; j < 8; ++j) v[j] = row[t + j * 256];
    float mx = v[0];
#pragma unroll
    for (int j = 1; j < 8; ++j) mx = fmaxf(mx, v[j]);
#pragma unroll
    for (int off = 1; off < 64; off <<= 1) mx = fmaxf(mx, __shfl_xor(mx, off, 64));
    __shared__ float redm[4], reds[4];
    int lane = t & 63, w = t >> 6;
    if (lane == 0) redm[w] = mx;
    __syncthreads();
    mx = fmaxf(fmaxf(redm[0], redm[1]), fmaxf(redm[2], redm[3]));
    float e[8], sum = 0.f;
#pragma unroll
    for (int j = 0; j < 8; ++j) { e[j] = __expf(v[j] - mx); sum += e[j]; }
#pragma unroll
    for (int off = 1; off < 64; off <<= 1) sum += __shfl_xor(sum, off, 64);
    if (lane == 0) reds[w] = sum;
    __syncthreads();
    float inv = 1.0f / (reds[0] + reds[1] + reds[2] + reds[3]);
#pragma unroll
    for (int j = 0; j < 8; ++j) row[t + j * 256] = e[j] * inv;
}

extern "C" void kernel_launch(void* const* d_in, const int* in_sizes, int n_in,
                              void* d_out, int out_size, void* d_ws, size_t ws_size,
                              hipStream_t stream) {
    const float* q  = (const float*)d_in[0];
    const float* k  = (const float*)d_in[1];
    const float* W1 = (const float*)d_in[2];
    const float* b1 = (const float*)d_in[3];
    const float* W2 = (const float*)d_in[4];
    const float* b2 = (const float*)d_in[5];
    const float* V  = (const float*)d_in[6];
    // d_in[7] = bv: scalar added to every score -> softmax-invariant, skipped.
    float* out = (float*)d_out;

    float* qpb = (float*)d_ws;                                     // 1 KB
    unsigned short* Bpack = (unsigned short*)((char*)d_ws + 1024); // 256 KB

    prep_qpb<<<1, 256, 0, stream>>>(q, W2, b1, b2, qpb);
    prep_bpack<<<32, 256, 0, stream>>>(W1, Bpack);
    fused_main<<<M_TOTAL / BM, 256, 0, stream>>>(k, Bpack, qpb, V, out);
    softmax_kernel<<<NBATCH, 256, 0, stream>>>(out);
}